// Round 1
// baseline (878.249 us; speedup 1.0000x reference)
//
#include <hip/hip_runtime.h>
#include <math.h>

#define L_ 4096
#define B_ 4
#define D_ 64
#define TI 64
#define TJ 64
#define NEGV (-1e9f)

typedef float f4 __attribute__((ext_vector_type(4)));

// -----------------------------------------------------------------------------
// Kernel 1: S = mask ? -1e9 : 0.125 * Q K^T   (raw logits -> attn region)
//           + online per-row (max, sumexp) -> workspace
// Grid: B * (L/TI) blocks of 256 threads. Thread (ty,tx) = (tid>>4, tid&15)
// owns rows ty*4..+3 and cols tx, tx+16, tx+32, tx+48 of the 64x64 tile.
// -----------------------------------------------------------------------------
__global__ __launch_bounds__(256) void qk_stats_kernel(
    const float* __restrict__ Q, const float* __restrict__ K,
    const int* __restrict__ mask, float* __restrict__ attn,
    float* __restrict__ m_ws, float* __restrict__ l_ws)
{
    __shared__ float qs[TI][D_ + 4];
    __shared__ float ks[TJ][D_ + 4];

    const int tid = threadIdx.x;
    const int ty = tid >> 4;   // 0..15 (row group)
    const int tx = tid & 15;   // 0..15 (col group)
    const int b  = blockIdx.x >> 6;   // L_/TI == 64
    const int it = blockIdx.x & 63;
    const int i0 = it * TI;

    // Load Q tile (64 rows x 64 floats), coalesced float4.
#pragma unroll
    for (int p = 0; p < 4; ++p) {
        int idx = p * 256 + tid;
        int r = idx >> 4, c4 = idx & 15;
        *reinterpret_cast<f4*>(&qs[r][c4 * 4]) =
            *reinterpret_cast<const f4*>(&Q[(size_t)(i0 + r) * (B_ * D_) + (size_t)b * D_ + c4 * 4]);
    }

    float m_run[4], l_run[4];
#pragma unroll
    for (int u = 0; u < 4; ++u) { m_run[u] = -INFINITY; l_run[u] = 0.f; }

    const size_t attn_row0 = (size_t)b * L_ * L_ + (size_t)i0 * L_;

    for (int jt = 0; jt < L_ / TJ; ++jt) {
        const int j0 = jt * TJ;
        __syncthreads();   // protect ks reuse (also covers qs readiness at jt=0)
#pragma unroll
        for (int p = 0; p < 4; ++p) {
            int idx = p * 256 + tid;
            int r = idx >> 4, c4 = idx & 15;
            *reinterpret_cast<f4*>(&ks[r][c4 * 4]) =
                *reinterpret_cast<const f4*>(&K[(size_t)(j0 + r) * (B_ * D_) + (size_t)b * D_ + c4 * 4]);
        }
        __syncthreads();

        float acc[4][4];
#pragma unroll
        for (int u = 0; u < 4; ++u)
#pragma unroll
            for (int w = 0; w < 4; ++w) acc[u][w] = 0.f;

#pragma unroll 4
        for (int dd = 0; dd < D_; dd += 4) {
            f4 qv[4], kv[4];
#pragma unroll
            for (int u = 0; u < 4; ++u)
                qv[u] = *reinterpret_cast<const f4*>(&qs[ty * 4 + u][dd]);
#pragma unroll
            for (int w = 0; w < 4; ++w)
                kv[w] = *reinterpret_cast<const f4*>(&ks[tx + 16 * w][dd]);
#pragma unroll
            for (int u = 0; u < 4; ++u)
#pragma unroll
                for (int w = 0; w < 4; ++w)
                    acc[u][w] += qv[u][0] * kv[w][0] + qv[u][1] * kv[w][1] +
                                 qv[u][2] * kv[w][2] + qv[u][3] * kv[w][3];
        }

        // mask + scale.  NOTE: mask read as int32 per harness contract
        // ("integer -> const int*"); if validation fails, switch to 1-byte bool.
        bool msk[4];
#pragma unroll
        for (int w = 0; w < 4; ++w)
            msk[w] = mask[(size_t)b * L_ + j0 + tx + 16 * w] != 0;

        float s[4][4];
#pragma unroll
        for (int u = 0; u < 4; ++u)
#pragma unroll
            for (int w = 0; w < 4; ++w)
                s[u][w] = msk[w] ? NEGV : acc[u][w] * 0.125f;

        // store raw logits to attn region
#pragma unroll
        for (int u = 0; u < 4; ++u) {
            size_t off = attn_row0 + (size_t)(ty * 4 + u) * L_ + j0 + tx;
#pragma unroll
            for (int w = 0; w < 4; ++w) attn[off + 16 * w] = s[u][w];
        }

        // online softmax stats: reduce across the 16 lanes sharing each row
#pragma unroll
        for (int u = 0; u < 4; ++u) {
            float tmax = fmaxf(fmaxf(s[u][0], s[u][1]), fmaxf(s[u][2], s[u][3]));
#pragma unroll
            for (int o = 1; o < 16; o <<= 1)
                tmax = fmaxf(tmax, __shfl_xor(tmax, o, 64));
            float nm = fmaxf(m_run[u], tmax);
            float tsum = 0.f;
#pragma unroll
            for (int w = 0; w < 4; ++w) tsum += expf(s[u][w] - nm);
#pragma unroll
            for (int o = 1; o < 16; o <<= 1)
                tsum += __shfl_xor(tsum, o, 64);
            l_run[u] = l_run[u] * expf(m_run[u] - nm) + tsum;
            m_run[u] = nm;
        }
    }

    if (tx == 0) {
#pragma unroll
        for (int u = 0; u < 4; ++u) {
            m_ws[(size_t)b * L_ + i0 + ty * 4 + u] = m_run[u];
            l_ws[(size_t)b * L_ + i0 + ty * 4 + u] = l_run[u];
        }
    }
}

// -----------------------------------------------------------------------------
// Kernel 2: normalize attn in place (p = exp(s - m) / l), out = P V.
// Same tiling. Out cols use the float4 mapping (tx*4..+3).
// -----------------------------------------------------------------------------
__global__ __launch_bounds__(256) void pv_kernel(
    const float* __restrict__ V, float* __restrict__ attn,
    const float* __restrict__ m_ws, const float* __restrict__ l_ws,
    float* __restrict__ out)
{
    __shared__ float ps[TI][TJ + 4];
    __shared__ float vs[TJ][D_ + 4];

    const int tid = threadIdx.x;
    const int ty = tid >> 4;
    const int tx = tid & 15;
    const int b  = blockIdx.x >> 6;
    const int it = blockIdx.x & 63;
    const int i0 = it * TI;

    float mrow[4], invl[4];
#pragma unroll
    for (int u = 0; u < 4; ++u) {
        mrow[u] = m_ws[(size_t)b * L_ + i0 + ty * 4 + u];
        invl[u] = 1.f / l_ws[(size_t)b * L_ + i0 + ty * 4 + u];
    }

    float acc[4][4];
#pragma unroll
    for (int u = 0; u < 4; ++u)
#pragma unroll
        for (int w = 0; w < 4; ++w) acc[u][w] = 0.f;

    const size_t attn_row0 = (size_t)b * L_ * L_ + (size_t)i0 * L_;

    for (int jt = 0; jt < L_ / TJ; ++jt) {
        const int j0 = jt * TJ;
        __syncthreads();   // protect ps/vs reuse
        // V tile
#pragma unroll
        for (int p = 0; p < 4; ++p) {
            int idx = p * 256 + tid;
            int r = idx >> 4, c4 = idx & 15;
            *reinterpret_cast<f4*>(&vs[r][c4 * 4]) =
                *reinterpret_cast<const f4*>(&V[(size_t)(j0 + r) * (B_ * D_) + (size_t)b * D_ + c4 * 4]);
        }
        // P = exp(s - m) * invl ; write back + stage in LDS
#pragma unroll
        for (int u = 0; u < 4; ++u) {
            size_t off = attn_row0 + (size_t)(ty * 4 + u) * L_ + j0 + tx;
#pragma unroll
            for (int w = 0; w < 4; ++w) {
                float sv = attn[off + 16 * w];
                float p = expf(sv - mrow[u]) * invl[u];
                attn[off + 16 * w] = p;
                ps[ty * 4 + u][tx + 16 * w] = p;
            }
        }
        __syncthreads();

        // out tile += P(64x64) * V(64x64)
#pragma unroll 4
        for (int kk = 0; kk < TJ; kk += 4) {
            f4 pr[4];
#pragma unroll
            for (int u = 0; u < 4; ++u)
                pr[u] = *reinterpret_cast<const f4*>(&ps[ty * 4 + u][kk]);
#pragma unroll
            for (int z = 0; z < 4; ++z) {
                f4 vv = *reinterpret_cast<const f4*>(&vs[kk + z][tx * 4]);
#pragma unroll
                for (int u = 0; u < 4; ++u) {
                    acc[u][0] += pr[u][z] * vv[0];
                    acc[u][1] += pr[u][z] * vv[1];
                    acc[u][2] += pr[u][z] * vv[2];
                    acc[u][3] += pr[u][z] * vv[3];
                }
            }
        }
    }

#pragma unroll
    for (int u = 0; u < 4; ++u) {
        f4 o4 = { acc[u][0], acc[u][1], acc[u][2], acc[u][3] };
        *reinterpret_cast<f4*>(&out[(size_t)(i0 + ty * 4 + u) * (B_ * D_) + (size_t)b * D_ + tx * 4]) = o4;
    }
}

extern "C" void kernel_launch(void* const* d_in, const int* in_sizes, int n_in,
                              void* d_out, int out_size, void* d_ws, size_t ws_size,
                              hipStream_t stream) {
    const float* Q = (const float*)d_in[0];
    const float* K = (const float*)d_in[1];
    const float* V = (const float*)d_in[2];
    const int*  mask = (const int*)d_in[3];   // jnp.bool_ -> int32 per harness contract

    float* out  = (float*)d_out;                            // [L, B, D]
    float* attn = (float*)d_out + (size_t)L_ * B_ * D_;     // [B, L, L]
    float* m_ws = (float*)d_ws;                             // B*L floats
    float* l_ws = m_ws + (size_t)B_ * L_;                   // B*L floats

    dim3 grid(B_ * (L_ / TI));
    dim3 block(256);
    hipLaunchKernelGGL(qk_stats_kernel, grid, block, 0, stream,
                       Q, K, mask, attn, m_ws, l_ws);
    hipLaunchKernelGGL(pv_kernel, grid, block, 0, stream,
                       V, attn, m_ws, l_ws, out);
}

// Round 2
// 633.244 us; speedup vs baseline: 1.3869x; 1.3869x over previous
//
#include <hip/hip_runtime.h>
#include <math.h>

#define L_ 4096
#define B_ 4
#define D_ 64
#define JS 4            // j-chunks for stats and pv kernels

typedef float f32x4 __attribute__((ext_vector_type(4)));
typedef short bf16x8 __attribute__((ext_vector_type(8)));
typedef unsigned short u16x8 __attribute__((ext_vector_type(8)));

#define MFMA16(a, b, c) __builtin_amdgcn_mfma_f32_16x16x32_bf16(a, b, c, 0, 0, 0)

__device__ inline unsigned short f2bf(float x) {
    union { float f; unsigned int u; } v; v.f = x;
    unsigned int r = v.u + 0x7FFFu + ((v.u >> 16) & 1u);   // RNE
    return (unsigned short)(r >> 16);
}
__device__ inline float bf2f(unsigned short h) {
    union { unsigned int u; float f; } v; v.u = ((unsigned int)h) << 16;
    return v.f;
}

// ---------------------------------------------------------------------------
// zero the out region (atomicAdd target). 1024*256 threads x 1 float4 each.
// ---------------------------------------------------------------------------
__global__ void zero_out_kernel(float* __restrict__ out) {
    const int i = blockIdx.x * 256 + threadIdx.x;
    ((f32x4*)out)[i] = (f32x4){0.f, 0.f, 0.f, 0.f};
}

// ---------------------------------------------------------------------------
// prep: Q,K fp32 [L,B,D] -> hi/lo bf16 [B][L][D];  V -> transposed [B][D][L].
// Block = (b, 64-row slab). 256 threads: thread t: row r=t>>2, d0=(t&3)*16.
// ---------------------------------------------------------------------------
__device__ inline void convert16(const float* __restrict__ src,
                                 unsigned short* __restrict__ dhi,
                                 unsigned short* __restrict__ dlo) {
    f32x4 a[4];
#pragma unroll
    for (int i = 0; i < 4; ++i) a[i] = *(const f32x4*)(src + 4 * i);
    u16x8 h0, h1, lo0, lo1;
#pragma unroll
    for (int m = 0; m < 16; ++m) {
        float x = a[m >> 2][m & 3];
        unsigned short h = f2bf(x);
        unsigned short l = f2bf(x - bf2f(h));
        if (m < 8) { h0[m] = (short)h; lo0[m] = (short)l; }
        else       { h1[m - 8] = (short)h; lo1[m - 8] = (short)l; }
    }
    *(u16x8*)(dhi)     = h0;  *(u16x8*)(dhi + 8) = h1;
    *(u16x8*)(dlo)     = lo0; *(u16x8*)(dlo + 8) = lo1;
}

__global__ __launch_bounds__(256) void prep_kernel(
    const float* __restrict__ Q, const float* __restrict__ K, const float* __restrict__ V,
    unsigned short* __restrict__ Qhi, unsigned short* __restrict__ Qlo,
    unsigned short* __restrict__ Khi, unsigned short* __restrict__ Klo,
    unsigned short* __restrict__ Vthi, unsigned short* __restrict__ Vtlo) {
    __shared__ __align__(16) float vt[64][68];
    const int t  = threadIdx.x;
    const int b  = blockIdx.x >> 6;
    const int l0 = (blockIdx.x & 63) << 6;
    const int r  = t >> 2;
    const int d0 = (t & 3) << 4;

    const size_t src = (size_t)(l0 + r) * (B_ * D_) + (size_t)b * D_ + d0;
    const size_t dst = ((size_t)b * L_ + l0 + r) * D_ + d0;
    convert16(Q + src, Qhi + dst, Qlo + dst);
    convert16(K + src, Khi + dst, Klo + dst);

    // stage V slab in LDS, then write transposed hi/lo
    const float* vsrc = V + src;
#pragma unroll
    for (int m = 0; m < 16; m += 4)
        *(f32x4*)&vt[r][d0 + m] = *(const f32x4*)&vsrc[m];
    __syncthreads();

    const int d  = t >> 2;
    const int lp = (t & 3) << 4;
    u16x8 h0, h1, lo0, lo1;
#pragma unroll
    for (int m = 0; m < 16; ++m) {
        float x = vt[lp + m][d];
        unsigned short h = f2bf(x);
        unsigned short l = f2bf(x - bf2f(h));
        if (m < 8) { h0[m] = (short)h; lo0[m] = (short)l; }
        else       { h1[m - 8] = (short)h; lo1[m - 8] = (short)l; }
    }
    unsigned short* oh = Vthi + ((size_t)b * D_ + d) * L_ + l0 + lp;
    unsigned short* ol = Vtlo + ((size_t)b * D_ + d) * L_ + l0 + lp;
    *(u16x8*)(oh) = h0;  *(u16x8*)(oh + 8) = h1;
    *(u16x8*)(ol) = lo0; *(u16x8*)(ol + 8) = lo1;
}

// ---------------------------------------------------------------------------
// stats: partial softmax denominator per (row, j-chunk).  l = sum exp(s-32).
// Grid B*64*JS blocks of 256 (4 waves); wave w owns 16 rows.
// MFMA 16x16x32 bf16, split hi/lo (3 terms x 2 k-halves = 6 MFMA / 16x16).
// ---------------------------------------------------------------------------
__global__ __launch_bounds__(256) void stats_kernel(
    const unsigned short* __restrict__ Qhi, const unsigned short* __restrict__ Qlo,
    const unsigned short* __restrict__ Khi, const unsigned short* __restrict__ Klo,
    const int* __restrict__ mask, float* __restrict__ lpart) {
    const int tid = threadIdx.x;
    const int w   = tid >> 6;
    const int lane = tid & 63;
    const int lr  = lane & 15;
    const int lg  = lane >> 4;
    const int jc  = blockIdx.x & (JS - 1);
    const int it  = (blockIdx.x >> 2) & 63;
    const int b   = blockIdx.x >> 8;
    const int irow = it * 64 + w * 16;
    const int j0c  = jc * (L_ / JS);

    const unsigned short* qp  = Qhi + ((size_t)b * L_ + irow + lr) * D_ + lg * 8;
    const unsigned short* qpl = Qlo + ((size_t)b * L_ + irow + lr) * D_ + lg * 8;
    const bf16x8 qh0 = *(const bf16x8*)qp;
    const bf16x8 qh1 = *(const bf16x8*)(qp + 32);
    const bf16x8 ql0 = *(const bf16x8*)qpl;
    const bf16x8 ql1 = *(const bf16x8*)(qpl + 32);

    float lsum[4] = {0.f, 0.f, 0.f, 0.f};

#pragma unroll 1
    for (int jt = 0; jt < (L_ / JS) / 64; ++jt) {
        const int j0 = j0c + jt * 64;
#pragma unroll
        for (int jj = 0; jj < 4; ++jj) {
            const int jcol = j0 + jj * 16 + lr;
            const unsigned short* kp  = Khi + ((size_t)b * L_ + jcol) * D_ + lg * 8;
            const unsigned short* kpl = Klo + ((size_t)b * L_ + jcol) * D_ + lg * 8;
            const bf16x8 kh0 = *(const bf16x8*)kp;
            const bf16x8 kh1 = *(const bf16x8*)(kp + 32);
            const bf16x8 kl0 = *(const bf16x8*)kpl;
            const bf16x8 kl1 = *(const bf16x8*)(kpl + 32);
            f32x4 acc = {0.f, 0.f, 0.f, 0.f};
            acc = MFMA16(qh0, kh0, acc);
            acc = MFMA16(qh1, kh1, acc);
            acc = MFMA16(qh0, kl0, acc);
            acc = MFMA16(qh1, kl1, acc);
            acc = MFMA16(ql0, kh0, acc);
            acc = MFMA16(ql1, kh1, acc);
            const float bias = mask[b * L_ + jcol] ? -1.0e9f : 0.0f;
#pragma unroll
            for (int r = 0; r < 4; ++r) {
                float s = fmaf(acc[r], 0.125f, bias) - 32.0f;
                lsum[r] += __expf(s);
            }
        }
    }
#pragma unroll
    for (int r = 0; r < 4; ++r) {
        float v = lsum[r];
        v += __shfl_xor(v, 1, 64);
        v += __shfl_xor(v, 2, 64);
        v += __shfl_xor(v, 4, 64);
        v += __shfl_xor(v, 8, 64);
        if (lr == 0)
            lpart[(((size_t)b * L_ + irow + lg * 4 + r) << 2) + jc] = v;
    }
}

// ---------------------------------------------------------------------------
// pv: recompute S, p = exp(s-32)/l, write attn (fp32, once), PV via MFMA
// (P and V both split hi/lo), atomicAdd partial out.
// ---------------------------------------------------------------------------
__global__ __launch_bounds__(256) void pv_kernel(
    const unsigned short* __restrict__ Qhi, const unsigned short* __restrict__ Qlo,
    const unsigned short* __restrict__ Khi, const unsigned short* __restrict__ Klo,
    const unsigned short* __restrict__ Vthi, const unsigned short* __restrict__ Vtlo,
    const int* __restrict__ mask, const float* __restrict__ lpart,
    float* __restrict__ attn, float* __restrict__ out) {
    __shared__ __align__(16) unsigned short phi[4][16][72];
    __shared__ __align__(16) unsigned short plo[4][16][72];

    const int tid = threadIdx.x;
    const int w   = tid >> 6;
    const int lane = tid & 63;
    const int lr  = lane & 15;
    const int lg  = lane >> 4;
    const int jc  = blockIdx.x & (JS - 1);
    const int it  = (blockIdx.x >> 2) & 63;
    const int b   = blockIdx.x >> 8;
    const int irow = it * 64 + w * 16;
    const int j0c  = jc * (L_ / JS);

    const unsigned short* qp  = Qhi + ((size_t)b * L_ + irow + lr) * D_ + lg * 8;
    const unsigned short* qpl = Qlo + ((size_t)b * L_ + irow + lr) * D_ + lg * 8;
    const bf16x8 qh0 = *(const bf16x8*)qp;
    const bf16x8 qh1 = *(const bf16x8*)(qp + 32);
    const bf16x8 ql0 = *(const bf16x8*)qpl;
    const bf16x8 ql1 = *(const bf16x8*)(qpl + 32);

    float invl[4];
#pragma unroll
    for (int r = 0; r < 4; ++r) {
        const float* lp = lpart + (((size_t)b * L_ + irow + lg * 4 + r) << 2);
        invl[r] = 1.0f / (lp[0] + lp[1] + lp[2] + lp[3]);
    }

    f32x4 oacc[4];
#pragma unroll
    for (int dv = 0; dv < 4; ++dv) oacc[dv] = (f32x4){0.f, 0.f, 0.f, 0.f};

    const size_t ab = (size_t)b * L_ * L_;

#pragma unroll 1
    for (int jt = 0; jt < (L_ / JS) / 64; ++jt) {
        const int j0 = j0c + jt * 64;
#pragma unroll
        for (int jj = 0; jj < 4; ++jj) {
            const int jcol = j0 + jj * 16 + lr;
            const unsigned short* kp  = Khi + ((size_t)b * L_ + jcol) * D_ + lg * 8;
            const unsigned short* kpl = Klo + ((size_t)b * L_ + jcol) * D_ + lg * 8;
            const bf16x8 kh0 = *(const bf16x8*)kp;
            const bf16x8 kh1 = *(const bf16x8*)(kp + 32);
            const bf16x8 kl0 = *(const bf16x8*)kpl;
            const bf16x8 kl1 = *(const bf16x8*)(kpl + 32);
            f32x4 acc = {0.f, 0.f, 0.f, 0.f};
            acc = MFMA16(qh0, kh0, acc);
            acc = MFMA16(qh1, kh1, acc);
            acc = MFMA16(qh0, kl0, acc);
            acc = MFMA16(qh1, kl1, acc);
            acc = MFMA16(ql0, kh0, acc);
            acc = MFMA16(ql1, kh1, acc);
            const float bias = mask[b * L_ + jcol] ? -1.0e9f : 0.0f;
#pragma unroll
            for (int r = 0; r < 4; ++r) {
                float p = __expf(fmaf(acc[r], 0.125f, bias) - 32.0f) * invl[r];
                attn[ab + (size_t)(irow + lg * 4 + r) * L_ + jcol] = p;
                unsigned short h = f2bf(p);
                unsigned short l = f2bf(p - bf2f(h));
                phi[w][lg * 4 + r][jj * 16 + lr] = h;
                plo[w][lg * 4 + r][jj * 16 + lr] = l;
            }
        }
        // P (LDS, hi/lo) x V (global, hi/lo): 3-term split, 2 k-halves, 4 dv-tiles
#pragma unroll
        for (int kk = 0; kk < 2; ++kk) {
            const bf16x8 aph = *(const bf16x8*)&phi[w][lr][kk * 32 + lg * 8];
            const bf16x8 apl = *(const bf16x8*)&plo[w][lr][kk * 32 + lg * 8];
#pragma unroll
            for (int dv = 0; dv < 4; ++dv) {
                const unsigned short* vp  = Vthi + ((size_t)b * D_ + dv * 16 + lr) * L_ + j0 + kk * 32 + lg * 8;
                const unsigned short* vpl = Vtlo + ((size_t)b * D_ + dv * 16 + lr) * L_ + j0 + kk * 32 + lg * 8;
                const bf16x8 vh = *(const bf16x8*)vp;
                const bf16x8 vl = *(const bf16x8*)vpl;
                oacc[dv] = MFMA16(aph, vh, oacc[dv]);
                oacc[dv] = MFMA16(aph, vl, oacc[dv]);
                oacc[dv] = MFMA16(apl, vh, oacc[dv]);
            }
        }
    }
#pragma unroll
    for (int dv = 0; dv < 4; ++dv)
#pragma unroll
        for (int r = 0; r < 4; ++r)
            atomicAdd(&out[(size_t)(irow + lg * 4 + r) * (B_ * D_) + b * D_ + dv * 16 + lr],
                      oacc[dv][r]);
}

// ---------------------------------------------------------------------------
extern "C" void kernel_launch(void* const* d_in, const int* in_sizes, int n_in,
                              void* d_out, int out_size, void* d_ws, size_t ws_size,
                              hipStream_t stream) {
    const float* Q   = (const float*)d_in[0];
    const float* K   = (const float*)d_in[1];
    const float* V   = (const float*)d_in[2];
    const int*  mask = (const int*)d_in[3];     // jnp.bool_ -> int32 (validated R1)

    float* out  = (float*)d_out;                             // [L, B, D]
    float* attn = (float*)d_out + (size_t)L_ * B_ * D_;      // [B, L, L]

    const size_t NE = (size_t)B_ * L_ * D_;                  // 1,048,576 elems
    unsigned short* Qhi  = (unsigned short*)d_ws;
    unsigned short* Qlo  = Qhi + NE;
    unsigned short* Khi  = Qhi + 2 * NE;
    unsigned short* Klo  = Qhi + 3 * NE;
    unsigned short* Vthi = Qhi + 4 * NE;
    unsigned short* Vtlo = Qhi + 5 * NE;
    float* lpart = (float*)((char*)d_ws + 6 * NE * sizeof(unsigned short)); // [B][L][JS]

    hipLaunchKernelGGL(zero_out_kernel, dim3((L_ * B_ * D_) / (256 * 4)), dim3(256), 0, stream, out);
    hipLaunchKernelGGL(prep_kernel, dim3(B_ * (L_ / 64)), dim3(256), 0, stream,
                       Q, K, V, Qhi, Qlo, Khi, Klo, Vthi, Vtlo);
    hipLaunchKernelGGL(stats_kernel, dim3(B_ * 64 * JS), dim3(256), 0, stream,
                       Qhi, Qlo, Khi, Klo, mask, lpart);
    hipLaunchKernelGGL(pv_kernel, dim3(B_ * 64 * JS), dim3(256), 0, stream,
                       Qhi, Qlo, Khi, Klo, Vthi, Vtlo, mask, lpart, attn, out);
}

// Round 3
// 579.422 us; speedup vs baseline: 1.5157x; 1.0929x over previous
//
#include <hip/hip_runtime.h>
#include <math.h>

#define L_ 4096
#define B_ 4
#define D_ 64
#define JS 8            // j-chunks per row-block for stats/pv

typedef float f32x4 __attribute__((ext_vector_type(4)));
typedef int   i32x4 __attribute__((ext_vector_type(4)));
typedef short bf16x8 __attribute__((ext_vector_type(8)));
typedef unsigned short u16x8 __attribute__((ext_vector_type(8)));
typedef unsigned short u16x4 __attribute__((ext_vector_type(4)));

#define MFMA16(a, b, c) __builtin_amdgcn_mfma_f32_16x16x32_bf16(a, b, c, 0, 0, 0)

__device__ inline unsigned short f2bf(float x) {
    union { float f; unsigned int u; } v; v.f = x;
    unsigned int r = v.u + 0x7FFFu + ((v.u >> 16) & 1u);   // RNE
    return (unsigned short)(r >> 16);
}
__device__ inline float bf2f(unsigned short h) {
    union { unsigned int u; float f; } v; v.u = ((unsigned int)h) << 16;
    return v.f;
}

// ---------------------------------------------------------------------------
// Stage a contiguous 64x64-bf16 tile (8 KB) global->LDS, linear LDS dest,
// XOR-swizzled global source (involution: byte ^= ((row&7)<<4), row=byte>>7).
// All 256 threads participate; per wave the LDS base is uniform (required).
// ---------------------------------------------------------------------------
__device__ inline void stage64(const unsigned short* __restrict__ g,
                               unsigned short* l, int tid) {
    const int w  = tid >> 6;
    const int ln = tid & 63;
#pragma unroll
    for (int r2 = 0; r2 < 2; ++r2) {
        const int base = r2 * 4096 + w * 1024;       // wave-uniform LDS byte base
        const int d = base + ln * 16;                // this lane's dest byte
        const int s = d ^ (((d >> 7) & 7) << 4);     // pre-swizzled source byte
        __builtin_amdgcn_global_load_lds(
            (const __attribute__((address_space(1))) void*)((const char*)g + s),
            (__attribute__((address_space(3))) void*)((char*)l + base),
            16, 0, 0);
    }
}

// Read a bf16x8 MFMA fragment from a swizzled 64x64 LDS tile.
__device__ inline bf16x8 rdfrag(const unsigned short* l, int row, int colh) {
    int off = (row << 7) + (colh << 1);
    off ^= (row & 7) << 4;
    return *(const bf16x8*)((const char*)l + off);
}

// ---------------------------------------------------------------------------
__global__ void zero_out_kernel(float* __restrict__ out) {
    const int i = blockIdx.x * 256 + threadIdx.x;
    ((f32x4*)out)[i] = (f32x4){0.f, 0.f, 0.f, 0.f};
}

// ---------------------------------------------------------------------------
// prep: Q,K fp32 [L,B,D] -> hi/lo bf16 [B][L][D];  V -> transposed [B][D][L].
// ---------------------------------------------------------------------------
__device__ inline void convert16(const float* __restrict__ src,
                                 unsigned short* __restrict__ dhi,
                                 unsigned short* __restrict__ dlo) {
    f32x4 a[4];
#pragma unroll
    for (int i = 0; i < 4; ++i) a[i] = *(const f32x4*)(src + 4 * i);
    u16x8 h0, h1, lo0, lo1;
#pragma unroll
    for (int m = 0; m < 16; ++m) {
        float x = a[m >> 2][m & 3];
        unsigned short h = f2bf(x);
        unsigned short l = f2bf(x - bf2f(h));
        if (m < 8) { h0[m] = (short)h; lo0[m] = (short)l; }
        else       { h1[m - 8] = (short)h; lo1[m - 8] = (short)l; }
    }
    *(u16x8*)(dhi)     = h0;  *(u16x8*)(dhi + 8) = h1;
    *(u16x8*)(dlo)     = lo0; *(u16x8*)(dlo + 8) = lo1;
}

__global__ __launch_bounds__(256) void prep_kernel(
    const float* __restrict__ Q, const float* __restrict__ K, const float* __restrict__ V,
    unsigned short* __restrict__ Qhi, unsigned short* __restrict__ Qlo,
    unsigned short* __restrict__ Khi, unsigned short* __restrict__ Klo,
    unsigned short* __restrict__ Vthi, unsigned short* __restrict__ Vtlo) {
    __shared__ __align__(16) float vt[64][68];
    const int t  = threadIdx.x;
    const int b  = blockIdx.x >> 6;
    const int l0 = (blockIdx.x & 63) << 6;
    const int r  = t >> 2;
    const int d0 = (t & 3) << 4;

    const size_t src = (size_t)(l0 + r) * (B_ * D_) + (size_t)b * D_ + d0;
    const size_t dst = ((size_t)b * L_ + l0 + r) * D_ + d0;
    convert16(Q + src, Qhi + dst, Qlo + dst);
    convert16(K + src, Khi + dst, Klo + dst);

    const float* vsrc = V + src;
#pragma unroll
    for (int m = 0; m < 16; m += 4)
        *(f32x4*)&vt[r][d0 + m] = *(const f32x4*)&vsrc[m];
    __syncthreads();

    const int d  = t >> 2;
    const int lp = (t & 3) << 4;
    u16x8 h0, h1, lo0, lo1;
#pragma unroll
    for (int m = 0; m < 16; ++m) {
        float x = vt[lp + m][d];
        unsigned short h = f2bf(x);
        unsigned short l = f2bf(x - bf2f(h));
        if (m < 8) { h0[m] = (short)h; lo0[m] = (short)l; }
        else       { h1[m - 8] = (short)h; lo1[m - 8] = (short)l; }
    }
    unsigned short* oh = Vthi + ((size_t)b * D_ + d) * L_ + l0 + lp;
    unsigned short* ol = Vtlo + ((size_t)b * D_ + d) * L_ + l0 + lp;
    *(u16x8*)(oh) = h0;  *(u16x8*)(oh + 8) = h1;
    *(u16x8*)(ol) = lo0; *(u16x8*)(ol + 8) = lo1;
}

// ---------------------------------------------------------------------------
// stats: partial softmax denominators.  Swapped MFMA (A=K, B=Q) so each lane
// holds 4 consecutive cols of one row (row = lr).  Block: 128 rows x 512-col
// chunk; wave = 32 rows (2 rowsets).  K tiles LDS double-buffered.
// Grid: B * 32 * JS = 1024 blocks of 256.
// ---------------------------------------------------------------------------
__global__ __launch_bounds__(256) void stats_kernel(
    const unsigned short* __restrict__ Qhi, const unsigned short* __restrict__ Qlo,
    const unsigned short* __restrict__ Khi, const unsigned short* __restrict__ Klo,
    const int* __restrict__ mask, float* __restrict__ lpart)
{
    __shared__ __align__(16) unsigned short kh[2][64 * 64];
    __shared__ __align__(16) unsigned short kl[2][64 * 64];

    const int tid = threadIdx.x;
    const int w = tid >> 6, lane = tid & 63;
    const int lr = lane & 15, lg = lane >> 4;
    const int b  = blockIdx.x >> 8;
    const int it = (blockIdx.x >> 3) & 31;
    const int jc = blockIdx.x & 7;
    const int irow = it * 128 + w * 32;
    const int j0c  = jc * (L_ / JS);

    bf16x8 qh0[2], qh1[2], ql0[2], ql1[2];
#pragma unroll
    for (int rs = 0; rs < 2; ++rs) {
        const size_t qoff = ((size_t)b * L_ + irow + rs * 16 + lr) * D_ + lg * 8;
        qh0[rs] = *(const bf16x8*)(Qhi + qoff);
        qh1[rs] = *(const bf16x8*)(Qhi + qoff + 32);
        ql0[rs] = *(const bf16x8*)(Qlo + qoff);
        ql1[rs] = *(const bf16x8*)(Qlo + qoff + 32);
    }

    float lsum[2] = {0.f, 0.f};
    int buf = 0;
    stage64(Khi + ((size_t)b * L_ + j0c) * D_, kh[0], tid);
    stage64(Klo + ((size_t)b * L_ + j0c) * D_, kl[0], tid);
    __syncthreads();

    for (int st = 0; st < (L_ / JS) / 64; ++st) {
        const int j0 = j0c + st * 64;
        if (st < (L_ / JS) / 64 - 1) {
            stage64(Khi + ((size_t)b * L_ + j0 + 64) * D_, kh[buf ^ 1], tid);
            stage64(Klo + ((size_t)b * L_ + j0 + 64) * D_, kl[buf ^ 1], tid);
        }
#pragma unroll
        for (int jj = 0; jj < 4; ++jj) {
            const bf16x8 a_h0 = rdfrag(kh[buf], jj * 16 + lr, lg * 8);
            const bf16x8 a_h1 = rdfrag(kh[buf], jj * 16 + lr, lg * 8 + 32);
            const bf16x8 a_l0 = rdfrag(kl[buf], jj * 16 + lr, lg * 8);
            const bf16x8 a_l1 = rdfrag(kl[buf], jj * 16 + lr, lg * 8 + 32);
            const i32x4 mv = *(const i32x4*)&mask[(size_t)b * L_ + j0 + jj * 16 + lg * 4];
            f32x4 bias;
#pragma unroll
            for (int r = 0; r < 4; ++r) bias[r] = mv[r] ? -1.0e9f : 0.0f;
#pragma unroll
            for (int rs = 0; rs < 2; ++rs) {
                f32x4 acc = {0.f, 0.f, 0.f, 0.f};
                acc = MFMA16(a_h0, qh0[rs], acc);
                acc = MFMA16(a_h1, qh1[rs], acc);
                acc = MFMA16(a_h0, ql0[rs], acc);
                acc = MFMA16(a_h1, ql1[rs], acc);
                acc = MFMA16(a_l0, qh0[rs], acc);
                acc = MFMA16(a_l1, qh1[rs], acc);
#pragma unroll
                for (int r = 0; r < 4; ++r)
                    lsum[rs] += __expf(fmaf(acc[r], 0.125f, bias[r]) - 32.0f);
            }
        }
        __syncthreads();
        buf ^= 1;
    }
#pragma unroll
    for (int rs = 0; rs < 2; ++rs) {
        float v = lsum[rs];
        v += __shfl_xor(v, 16, 64);
        v += __shfl_xor(v, 32, 64);
        if (lg == 0)
            lpart[((size_t)b * L_ + irow + rs * 16 + lr) * JS + jc] = v;
    }
}

// ---------------------------------------------------------------------------
// pv: recompute S (swapped), p = exp(s-32)*invl, attn store dwordx4, P packed
// to LDS (b64 writes), PV via swapped MFMA (A=V^T, B=P) -> out cols are
// consecutive per lane; atomicAdd partials.
// ---------------------------------------------------------------------------
__global__ __launch_bounds__(256) void pv_kernel(
    const unsigned short* __restrict__ Qhi, const unsigned short* __restrict__ Qlo,
    const unsigned short* __restrict__ Khi, const unsigned short* __restrict__ Klo,
    const unsigned short* __restrict__ Vthi, const unsigned short* __restrict__ Vtlo,
    const int* __restrict__ mask, const float* __restrict__ lpart,
    float* __restrict__ attn, float* __restrict__ out)
{
    __shared__ __align__(16) unsigned short kh[2][64 * 64];
    __shared__ __align__(16) unsigned short kl[2][64 * 64];
    __shared__ __align__(16) unsigned short phs[4][16][72];
    __shared__ __align__(16) unsigned short pls[4][16][72];

    const int tid = threadIdx.x;
    const int w = tid >> 6, lane = tid & 63;
    const int lr = lane & 15, lg = lane >> 4;
    const int b  = blockIdx.x >> 8;
    const int it = (blockIdx.x >> 3) & 31;
    const int jc = blockIdx.x & 7;
    const int irow = it * 128 + w * 32;
    const int j0c  = jc * (L_ / JS);
    const size_t ab = (size_t)b * L_ * L_;

    bf16x8 qh0[2], qh1[2], ql0[2], ql1[2];
    float invl[2];
#pragma unroll
    for (int rs = 0; rs < 2; ++rs) {
        const size_t row = (size_t)b * L_ + irow + rs * 16 + lr;
        const size_t qoff = row * D_ + lg * 8;
        qh0[rs] = *(const bf16x8*)(Qhi + qoff);
        qh1[rs] = *(const bf16x8*)(Qhi + qoff + 32);
        ql0[rs] = *(const bf16x8*)(Qlo + qoff);
        ql1[rs] = *(const bf16x8*)(Qlo + qoff + 32);
        const float* lp = lpart + row * JS;
        f32x4 s0 = *(const f32x4*)lp;
        f32x4 s1 = *(const f32x4*)(lp + 4);
        invl[rs] = 1.0f / (s0[0] + s0[1] + s0[2] + s0[3] + s1[0] + s1[1] + s1[2] + s1[3]);
    }

    f32x4 oacc[2][4];
#pragma unroll
    for (int rs = 0; rs < 2; ++rs)
#pragma unroll
        for (int dv = 0; dv < 4; ++dv) oacc[rs][dv] = (f32x4){0.f, 0.f, 0.f, 0.f};

    int buf = 0;
    stage64(Khi + ((size_t)b * L_ + j0c) * D_, kh[0], tid);
    stage64(Klo + ((size_t)b * L_ + j0c) * D_, kl[0], tid);
    __syncthreads();

    for (int st = 0; st < (L_ / JS) / 64; ++st) {
        const int j0 = j0c + st * 64;
        if (st < (L_ / JS) / 64 - 1) {
            stage64(Khi + ((size_t)b * L_ + j0 + 64) * D_, kh[buf ^ 1], tid);
            stage64(Klo + ((size_t)b * L_ + j0 + 64) * D_, kl[buf ^ 1], tid);
        }
#pragma unroll
        for (int rs = 0; rs < 2; ++rs) {
            // --- QK + softmax + attn store + P pack ---
#pragma unroll
            for (int jj = 0; jj < 4; ++jj) {
                const bf16x8 a_h0 = rdfrag(kh[buf], jj * 16 + lr, lg * 8);
                const bf16x8 a_h1 = rdfrag(kh[buf], jj * 16 + lr, lg * 8 + 32);
                const bf16x8 a_l0 = rdfrag(kl[buf], jj * 16 + lr, lg * 8);
                const bf16x8 a_l1 = rdfrag(kl[buf], jj * 16 + lr, lg * 8 + 32);
                const i32x4 mv = *(const i32x4*)&mask[(size_t)b * L_ + j0 + jj * 16 + lg * 4];
                f32x4 acc = {0.f, 0.f, 0.f, 0.f};
                acc = MFMA16(a_h0, qh0[rs], acc);
                acc = MFMA16(a_h1, qh1[rs], acc);
                acc = MFMA16(a_h0, ql0[rs], acc);
                acc = MFMA16(a_h1, ql1[rs], acc);
                acc = MFMA16(a_l0, qh0[rs], acc);
                acc = MFMA16(a_l1, qh1[rs], acc);
                f32x4 p4;
                u16x4 hv, lv;
#pragma unroll
                for (int r = 0; r < 4; ++r) {
                    const float bias = mv[r] ? -1.0e9f : 0.0f;
                    const float p = __expf(fmaf(acc[r], 0.125f, bias) - 32.0f) * invl[rs];
                    p4[r] = p;
                    const unsigned short h = f2bf(p);
                    hv[r] = h;
                    lv[r] = f2bf(p - bf2f(h));
                }
                *(f32x4*)&attn[ab + (size_t)(irow + rs * 16 + lr) * L_ + j0 + jj * 16 + lg * 4] = p4;
                *(u16x4*)&phs[w][lr][jj * 16 + lg * 4] = hv;
                *(u16x4*)&pls[w][lr][jj * 16 + lg * 4] = lv;
            }
            // --- PV for this rowset (P is per-wave private; in-wave DS order) ---
#pragma unroll
            for (int kk = 0; kk < 2; ++kk) {
                const bf16x8 ph = *(const bf16x8*)&phs[w][lr][kk * 32 + lg * 8];
                const bf16x8 pl = *(const bf16x8*)&pls[w][lr][kk * 32 + lg * 8];
#pragma unroll
                for (int dv = 0; dv < 4; ++dv) {
                    const size_t voff = ((size_t)b * D_ + dv * 16 + lr) * L_ + j0 + kk * 32 + lg * 8;
                    const bf16x8 vh = *(const bf16x8*)(Vthi + voff);
                    const bf16x8 vl = *(const bf16x8*)(Vtlo + voff);
                    oacc[rs][dv] = MFMA16(vh, ph, oacc[rs][dv]);
                    oacc[rs][dv] = MFMA16(vh, pl, oacc[rs][dv]);
                    oacc[rs][dv] = MFMA16(vl, ph, oacc[rs][dv]);
                }
            }
        }
        __syncthreads();
        buf ^= 1;
    }

#pragma unroll
    for (int rs = 0; rs < 2; ++rs)
#pragma unroll
        for (int dv = 0; dv < 4; ++dv) {
            const size_t obase = (size_t)(irow + rs * 16 + lr) * (B_ * D_) + b * D_ + dv * 16 + lg * 4;
#pragma unroll
            for (int r = 0; r < 4; ++r)
                atomicAdd(&out[obase + r], oacc[rs][dv][r]);
        }
}

// ---------------------------------------------------------------------------
extern "C" void kernel_launch(void* const* d_in, const int* in_sizes, int n_in,
                              void* d_out, int out_size, void* d_ws, size_t ws_size,
                              hipStream_t stream) {
    const float* Q   = (const float*)d_in[0];
    const float* K   = (const float*)d_in[1];
    const float* V   = (const float*)d_in[2];
    const int*  mask = (const int*)d_in[3];     // jnp.bool_ -> int32 (validated R1)

    float* out  = (float*)d_out;                             // [L, B, D]
    float* attn = (float*)d_out + (size_t)L_ * B_ * D_;      // [B, L, L]

    const size_t NE = (size_t)B_ * L_ * D_;
    unsigned short* Qhi  = (unsigned short*)d_ws;
    unsigned short* Qlo  = Qhi + NE;
    unsigned short* Khi  = Qhi + 2 * NE;
    unsigned short* Klo  = Qhi + 3 * NE;
    unsigned short* Vthi = Qhi + 4 * NE;
    unsigned short* Vtlo = Qhi + 5 * NE;
    float* lpart = (float*)((char*)d_ws + 6 * NE * sizeof(unsigned short)); // [B*L][JS]

    hipLaunchKernelGGL(zero_out_kernel, dim3((L_ * B_ * D_) / (256 * 4)), dim3(256), 0, stream, out);
    hipLaunchKernelGGL(prep_kernel, dim3(B_ * (L_ / 64)), dim3(256), 0, stream,
                       Q, K, V, Qhi, Qlo, Khi, Klo, Vthi, Vtlo);
    hipLaunchKernelGGL(stats_kernel, dim3(B_ * (L_ / 128) * JS), dim3(256), 0, stream,
                       Qhi, Qlo, Khi, Klo, mask, lpart);
    hipLaunchKernelGGL(pv_kernel, dim3(B_ * (L_ / 128) * JS), dim3(256), 0, stream,
                       Qhi, Qlo, Khi, Klo, Vthi, Vtlo, mask, lpart, attn, out);
}

// Round 4
// 525.615 us; speedup vs baseline: 1.6709x; 1.1024x over previous
//
#include <hip/hip_runtime.h>
#include <math.h>

#define L_ 4096
#define B_ 4
#define D_ 64
#define JS 8            // j-chunks per 128-row block

typedef float f32x4 __attribute__((ext_vector_type(4)));
typedef int   i32x4 __attribute__((ext_vector_type(4)));
typedef short bf16x8 __attribute__((ext_vector_type(8)));
typedef unsigned short u16x8 __attribute__((ext_vector_type(8)));
typedef unsigned short u16x4 __attribute__((ext_vector_type(4)));

#define MFMA16(a, b, c) __builtin_amdgcn_mfma_f32_16x16x32_bf16(a, b, c, 0, 0, 0)

__device__ inline unsigned short f2bf(float x) {
    union { float f; unsigned int u; } v; v.f = x;
    unsigned int r = v.u + 0x7FFFu + ((v.u >> 16) & 1u);   // RNE
    return (unsigned short)(r >> 16);
}
__device__ inline float bf2f(unsigned short h) {
    union { unsigned int u; float f; } v; v.u = ((unsigned int)h) << 16;
    return v.f;
}

// ---------------------------------------------------------------------------
// Stage a contiguous 64x64-bf16 tile (8 KB) global->LDS, linear LDS dest,
// XOR-swizzled global source (involution: byte ^= ((byte>>7)&7)<<4).
// ---------------------------------------------------------------------------
__device__ inline void stage64(const unsigned short* __restrict__ g,
                               unsigned short* l, int tid) {
    const int w  = tid >> 6;
    const int ln = tid & 63;
#pragma unroll
    for (int r2 = 0; r2 < 2; ++r2) {
        const int base = r2 * 4096 + w * 1024;       // wave-uniform LDS byte base
        const int d = base + ln * 16;
        const int s = d ^ (((d >> 7) & 7) << 4);
        __builtin_amdgcn_global_load_lds(
            (const __attribute__((address_space(1))) void*)((const char*)g + s),
            (__attribute__((address_space(3))) void*)((char*)l + base),
            16, 0, 0);
    }
}

// Read a bf16x8 MFMA fragment from the swizzled 64x64 LDS tile.
__device__ inline bf16x8 rdfrag(const unsigned short* l, int row, int colh) {
    int off = (row << 7) + (colh << 1);
    off ^= (row & 7) << 4;
    return *(const bf16x8*)((const char*)l + off);
}

// ---------------------------------------------------------------------------
__global__ void zero_out_kernel(float* __restrict__ out) {
    const int i = blockIdx.x * 256 + threadIdx.x;
    ((f32x4*)out)[i] = (f32x4){0.f, 0.f, 0.f, 0.f};
}

// ---------------------------------------------------------------------------
// prep: Q (x0.125), K -> hi/lo bf16 [B][L][D];  V -> transposed hi/lo [B][D][L]
// ---------------------------------------------------------------------------
__device__ inline void convert16(const float* __restrict__ src, float scale,
                                 unsigned short* __restrict__ dhi,
                                 unsigned short* __restrict__ dlo) {
    f32x4 a[4];
#pragma unroll
    for (int i = 0; i < 4; ++i) a[i] = *(const f32x4*)(src + 4 * i);
    u16x8 h0, h1, lo0, lo1;
#pragma unroll
    for (int m = 0; m < 16; ++m) {
        float x = a[m >> 2][m & 3] * scale;
        unsigned short h = f2bf(x);
        unsigned short l = f2bf(x - bf2f(h));
        if (m < 8) { h0[m] = (short)h; lo0[m] = (short)l; }
        else       { h1[m - 8] = (short)h; lo1[m - 8] = (short)l; }
    }
    *(u16x8*)(dhi)     = h0;  *(u16x8*)(dhi + 8) = h1;
    *(u16x8*)(dlo)     = lo0; *(u16x8*)(dlo + 8) = lo1;
}

__global__ __launch_bounds__(256) void prep_kernel(
    const float* __restrict__ Q, const float* __restrict__ K, const float* __restrict__ V,
    unsigned short* __restrict__ Qhi, unsigned short* __restrict__ Qlo,
    unsigned short* __restrict__ Khi, unsigned short* __restrict__ Klo,
    unsigned short* __restrict__ Vthi, unsigned short* __restrict__ Vtlo) {
    __shared__ __align__(16) float vt[64][68];
    const int t  = threadIdx.x;
    const int b  = blockIdx.x >> 6;
    const int l0 = (blockIdx.x & 63) << 6;
    const int r  = t >> 2;
    const int d0 = (t & 3) << 4;

    const size_t src = (size_t)(l0 + r) * (B_ * D_) + (size_t)b * D_ + d0;
    const size_t dst = ((size_t)b * L_ + l0 + r) * D_ + d0;
    convert16(Q + src, 0.125f, Qhi + dst, Qlo + dst);
    convert16(K + src, 1.0f,   Khi + dst, Klo + dst);

    const float* vsrc = V + src;
#pragma unroll
    for (int m = 0; m < 16; m += 4)
        *(f32x4*)&vt[r][d0 + m] = *(const f32x4*)&vsrc[m];
    __syncthreads();

    const int d  = t >> 2;
    const int lp = (t & 3) << 4;
    u16x8 h0, h1, lo0, lo1;
#pragma unroll
    for (int m = 0; m < 16; ++m) {
        float x = vt[lp + m][d];
        unsigned short h = f2bf(x);
        unsigned short l = f2bf(x - bf2f(h));
        if (m < 8) { h0[m] = (short)h; lo0[m] = (short)l; }
        else       { h1[m - 8] = (short)h; lo1[m - 8] = (short)l; }
    }
    unsigned short* oh = Vthi + ((size_t)b * D_ + d) * L_ + l0 + lp;
    unsigned short* ol = Vtlo + ((size_t)b * D_ + d) * L_ + l0 + lp;
    *(u16x8*)(oh) = h0;  *(u16x8*)(oh + 8) = h1;
    *(u16x8*)(ol) = lo0; *(u16x8*)(ol + 8) = lo1;
}

// ---------------------------------------------------------------------------
// fused: S = QK^T (swapped MFMA), e = exp(s) (masked -> 0), store e to attn
// (unnormalized), accumulate row-sums -> lpart, PV via MFMA -> atomicAdd out
// (unnormalized).  Block = 128 rows x 512-col chunk; wave = 32 rows.
// Grid: B * 32 * JS = 1024 blocks of 256 threads.
// ---------------------------------------------------------------------------
__global__ __launch_bounds__(256) void fused_kernel(
    const unsigned short* __restrict__ Qhi, const unsigned short* __restrict__ Qlo,
    const unsigned short* __restrict__ Khi, const unsigned short* __restrict__ Klo,
    const unsigned short* __restrict__ Vthi, const unsigned short* __restrict__ Vtlo,
    const int* __restrict__ mask, float* __restrict__ attn,
    float* __restrict__ lpart, float* __restrict__ out)
{
    __shared__ __align__(16) unsigned short kh[64 * 64];     // 8 KB
    __shared__ __align__(16) unsigned short kl[64 * 64];     // 8 KB
    __shared__ __align__(16) unsigned short phs[4][16][72];  // 9 KB
    __shared__ __align__(16) unsigned short pls[4][16][72];  // 9 KB

    const int tid = threadIdx.x;
    const int w = tid >> 6, lane = tid & 63;
    const int lr = lane & 15, lg = lane >> 4;
    const int b  = blockIdx.x >> 8;
    const int it = (blockIdx.x >> 3) & 31;
    const int jc = blockIdx.x & 7;
    const int irow = it * 128 + w * 32;
    const int j0c  = jc * (L_ / JS);
    const size_t ab = (size_t)b * L_ * L_;

    bf16x8 qh0[2], qh1[2], ql0[2], ql1[2];
#pragma unroll
    for (int rs = 0; rs < 2; ++rs) {
        const size_t qoff = ((size_t)b * L_ + irow + rs * 16 + lr) * D_ + lg * 8;
        qh0[rs] = *(const bf16x8*)(Qhi + qoff);
        qh1[rs] = *(const bf16x8*)(Qhi + qoff + 32);
        ql0[rs] = *(const bf16x8*)(Qlo + qoff);
        ql1[rs] = *(const bf16x8*)(Qlo + qoff + 32);
    }

    f32x4 oacc[2][4];
#pragma unroll
    for (int rs = 0; rs < 2; ++rs)
#pragma unroll
        for (int dv = 0; dv < 4; ++dv) oacc[rs][dv] = (f32x4){0.f, 0.f, 0.f, 0.f};
    float lsum[2] = {0.f, 0.f};

    for (int st = 0; st < (L_ / JS) / 64; ++st) {
        const int j0 = j0c + st * 64;
        __syncthreads();                              // protect K buf from prev readers
        stage64(Khi + ((size_t)b * L_ + j0) * D_, kh, tid);
        stage64(Klo + ((size_t)b * L_ + j0) * D_, kl, tid);
        __syncthreads();                              // staged data visible

        i32x4 mv[4];
#pragma unroll
        for (int jj = 0; jj < 4; ++jj)
            mv[jj] = *(const i32x4*)&mask[(size_t)b * L_ + j0 + jj * 16 + lg * 4];

        bf16x8 P[2][4];                               // [rs][kk*2 + {hi,lo}]
#pragma unroll
        for (int rs = 0; rs < 2; ++rs) {
            // --- QK + exp + attn store + P pack (P LDS buffer reused per rs) ---
#pragma unroll
            for (int jj = 0; jj < 4; ++jj) {
                const bf16x8 a_h0 = rdfrag(kh, jj * 16 + lr, lg * 8);
                const bf16x8 a_h1 = rdfrag(kh, jj * 16 + lr, lg * 8 + 32);
                const bf16x8 a_l0 = rdfrag(kl, jj * 16 + lr, lg * 8);
                const bf16x8 a_l1 = rdfrag(kl, jj * 16 + lr, lg * 8 + 32);
                f32x4 acc = {0.f, 0.f, 0.f, 0.f};
                acc = MFMA16(a_h0, qh0[rs], acc);
                acc = MFMA16(a_h1, qh1[rs], acc);
                acc = MFMA16(a_h0, ql0[rs], acc);
                acc = MFMA16(a_h1, ql1[rs], acc);
                acc = MFMA16(a_l0, qh0[rs], acc);
                acc = MFMA16(a_l1, qh1[rs], acc);
                f32x4 e4;
                u16x4 hv, lv;
#pragma unroll
                for (int r = 0; r < 4; ++r) {
                    const float s = mv[jj][r] ? -1.0e9f : acc[r];
                    const float e = __expf(s);        // masked -> exactly 0
                    e4[r] = e;
                    const unsigned short h = f2bf(e);
                    hv[r] = h;
                    lv[r] = f2bf(e - bf2f(h));
                }
                lsum[rs] += e4[0] + e4[1] + e4[2] + e4[3];
                *(f32x4*)&attn[ab + (size_t)(irow + rs * 16 + lr) * L_ + j0 + jj * 16 + lg * 4] = e4;
                *(u16x4*)&phs[w][lr][jj * 16 + lg * 4] = hv;
                *(u16x4*)&pls[w][lr][jj * 16 + lg * 4] = lv;
            }
            // pull this rowset's P fragments into registers (frees LDS for rs+1)
            P[rs][0] = *(const bf16x8*)&phs[w][lr][lg * 8];
            P[rs][1] = *(const bf16x8*)&pls[w][lr][lg * 8];
            P[rs][2] = *(const bf16x8*)&phs[w][lr][32 + lg * 8];
            P[rs][3] = *(const bf16x8*)&pls[w][lr][32 + lg * 8];
        }
        // --- PV: each V fragment load serves both rowsets ---
#pragma unroll
        for (int kk = 0; kk < 2; ++kk) {
#pragma unroll
            for (int dv = 0; dv < 4; ++dv) {
                const size_t voff = ((size_t)b * D_ + dv * 16 + lr) * L_ + j0 + kk * 32 + lg * 8;
                const bf16x8 vh = *(const bf16x8*)(Vthi + voff);
                const bf16x8 vl = *(const bf16x8*)(Vtlo + voff);
#pragma unroll
                for (int rs = 0; rs < 2; ++rs) {
                    oacc[rs][dv] = MFMA16(vh, P[rs][kk * 2], oacc[rs][dv]);
                    oacc[rs][dv] = MFMA16(vh, P[rs][kk * 2 + 1], oacc[rs][dv]);
                    oacc[rs][dv] = MFMA16(vl, P[rs][kk * 2], oacc[rs][dv]);
                }
            }
        }
    }

    // epilogue: partial row-sums + unnormalized O
#pragma unroll
    for (int rs = 0; rs < 2; ++rs) {
        float v = lsum[rs];
        v += __shfl_xor(v, 16, 64);
        v += __shfl_xor(v, 32, 64);
        if (lg == 0)
            lpart[((size_t)b * L_ + irow + rs * 16 + lr) * JS + jc] = v;
#pragma unroll
        for (int dv = 0; dv < 4; ++dv) {
            const size_t obase = (size_t)(irow + rs * 16 + lr) * (B_ * D_) + b * D_ + dv * 16 + lg * 4;
#pragma unroll
            for (int r = 0; r < 4; ++r)
                atomicAdd(&out[obase + r], oacc[rs][dv][r]);
        }
    }
}

// ---------------------------------------------------------------------------
// rescale: attn *= 1/l, in place.  One block per (b,i) row.
// ---------------------------------------------------------------------------
__global__ __launch_bounds__(256) void rescale_kernel(
    float* __restrict__ attn, const float* __restrict__ lpart)
{
    const int row = blockIdx.x;                       // b*L + i
    const float* lp = lpart + (size_t)row * JS;
    float l = 0.f;
#pragma unroll
    for (int k = 0; k < JS; ++k) l += lp[k];
    const float invl = 1.0f / l;

    float* base = attn + (size_t)row * L_;
    const int t = threadIdx.x;
#pragma unroll
    for (int k = 0; k < 4; ++k) {
        f32x4 v = *(f32x4*)&base[(k * 256 + t) * 4];
        v[0] *= invl; v[1] *= invl; v[2] *= invl; v[3] *= invl;
        *(f32x4*)&base[(k * 256 + t) * 4] = v;
    }
}

// ---------------------------------------------------------------------------
// finalize: out *= 1/l   (out is [L,B,D]; l depends on (b,l))
// ---------------------------------------------------------------------------
__global__ __launch_bounds__(256) void finalize_kernel(
    float* __restrict__ out, const float* __restrict__ lpart)
{
    const int idx = blockIdx.x * 256 + threadIdx.x;   // f32x4 index
    const int lb  = idx >> 4;                         // l*B + b
    const int l   = lb >> 2, b = lb & 3;
    const float* lp = lpart + ((size_t)b * L_ + l) * JS;
    float s = 0.f;
#pragma unroll
    for (int k = 0; k < JS; ++k) s += lp[k];
    const float invl = 1.0f / s;
    f32x4 v = ((f32x4*)out)[idx];
    v[0] *= invl; v[1] *= invl; v[2] *= invl; v[3] *= invl;
    ((f32x4*)out)[idx] = v;
}

// ---------------------------------------------------------------------------
extern "C" void kernel_launch(void* const* d_in, const int* in_sizes, int n_in,
                              void* d_out, int out_size, void* d_ws, size_t ws_size,
                              hipStream_t stream) {
    const float* Q   = (const float*)d_in[0];
    const float* K   = (const float*)d_in[1];
    const float* V   = (const float*)d_in[2];
    const int*  mask = (const int*)d_in[3];     // jnp.bool_ -> int32 (validated R1)

    float* out  = (float*)d_out;                             // [L, B, D]
    float* attn = (float*)d_out + (size_t)L_ * B_ * D_;      // [B, L, L]

    const size_t NE = (size_t)B_ * L_ * D_;
    unsigned short* Qhi  = (unsigned short*)d_ws;
    unsigned short* Qlo  = Qhi + NE;
    unsigned short* Khi  = Qhi + 2 * NE;
    unsigned short* Klo  = Qhi + 3 * NE;
    unsigned short* Vthi = Qhi + 4 * NE;
    unsigned short* Vtlo = Qhi + 5 * NE;
    float* lpart = (float*)((char*)d_ws + 6 * NE * sizeof(unsigned short)); // [B*L][JS]

    hipLaunchKernelGGL(zero_out_kernel, dim3((L_ * B_ * D_) / (256 * 4)), dim3(256), 0, stream, out);
    hipLaunchKernelGGL(prep_kernel, dim3(B_ * (L_ / 64)), dim3(256), 0, stream,
                       Q, K, V, Qhi, Qlo, Khi, Klo, Vthi, Vtlo);
    hipLaunchKernelGGL(fused_kernel, dim3(B_ * (L_ / 128) * JS), dim3(256), 0, stream,
                       Qhi, Qlo, Khi, Klo, Vthi, Vtlo, mask, attn, lpart, out);
    hipLaunchKernelGGL(rescale_kernel, dim3(B_ * L_), dim3(256), 0, stream, attn, lpart);
    hipLaunchKernelGGL(finalize_kernel, dim3((L_ * B_ * D_) / (256 * 4)), dim3(256), 0, stream,
                       out, lpart);
}

// Round 5
// 469.069 us; speedup vs baseline: 1.8723x; 1.1205x over previous
//
#include <hip/hip_runtime.h>
#include <math.h>

#define L_ 4096
#define B_ 4
#define D_ 64
#define JS 8            // j-chunks per 128-row block
#define NS ((L_ / JS) / 64)   // 8 K-tiles of 64 per chunk

typedef float f32x4 __attribute__((ext_vector_type(4)));
typedef int   i32x4 __attribute__((ext_vector_type(4)));
typedef short bf16x8 __attribute__((ext_vector_type(8)));
typedef unsigned short u16x8 __attribute__((ext_vector_type(8)));
typedef unsigned short u16x4 __attribute__((ext_vector_type(4)));

#define MFMA16(a, b, c) __builtin_amdgcn_mfma_f32_16x16x32_bf16(a, b, c, 0, 0, 0)

__device__ inline unsigned short f2bf(float x) {
    union { float f; unsigned int u; } v; v.f = x;
    unsigned int r = v.u + 0x7FFFu + ((v.u >> 16) & 1u);   // RNE
    return (unsigned short)(r >> 16);
}
__device__ inline float bf2f(unsigned short h) {
    union { unsigned int u; float f; } v; v.u = ((unsigned int)h) << 16;
    return v.f;
}

// ---------------------------------------------------------------------------
// Stage a contiguous 64x64-bf16 tile (8 KB) global->LDS, linear LDS dest,
// XOR-swizzled global source (involution: byte ^= ((byte>>7)&7)<<4).
// ---------------------------------------------------------------------------
__device__ inline void stage64(const unsigned short* __restrict__ g,
                               unsigned short* l, int tid) {
    const int w  = tid >> 6;
    const int ln = tid & 63;
#pragma unroll
    for (int r2 = 0; r2 < 2; ++r2) {
        const int base = r2 * 4096 + w * 1024;       // wave-uniform LDS byte base
        const int d = base + ln * 16;
        const int s = d ^ (((d >> 7) & 7) << 4);
        __builtin_amdgcn_global_load_lds(
            (const __attribute__((address_space(1))) void*)((const char*)g + s),
            (__attribute__((address_space(3))) void*)((char*)l + base),
            16, 0, 0);
    }
}

// Read a bf16x8 MFMA fragment from the swizzled 64x64 LDS tile.
__device__ inline bf16x8 rdfrag(const unsigned short* l, int row, int colh) {
    int off = (row << 7) + (colh << 1);
    off ^= (row & 7) << 4;
    return *(const bf16x8*)((const char*)l + off);
}

// ---------------------------------------------------------------------------
__global__ void zero_out_kernel(float* __restrict__ out) {
    const int i = blockIdx.x * 256 + threadIdx.x;
    ((f32x4*)out)[i] = (f32x4){0.f, 0.f, 0.f, 0.f};
}

// ---------------------------------------------------------------------------
// prep: Q (x0.125), K -> hi/lo bf16 [B][L][D];  V -> transposed hi/lo [B][D][L]
// ---------------------------------------------------------------------------
__device__ inline void convert16(const float* __restrict__ src, float scale,
                                 unsigned short* __restrict__ dhi,
                                 unsigned short* __restrict__ dlo) {
    f32x4 a[4];
#pragma unroll
    for (int i = 0; i < 4; ++i) a[i] = *(const f32x4*)(src + 4 * i);
    u16x8 h0, h1, lo0, lo1;
#pragma unroll
    for (int m = 0; m < 16; ++m) {
        float x = a[m >> 2][m & 3] * scale;
        unsigned short h = f2bf(x);
        unsigned short l = f2bf(x - bf2f(h));
        if (m < 8) { h0[m] = (short)h; lo0[m] = (short)l; }
        else       { h1[m - 8] = (short)h; lo1[m - 8] = (short)l; }
    }
    *(u16x8*)(dhi)     = h0;  *(u16x8*)(dhi + 8) = h1;
    *(u16x8*)(dlo)     = lo0; *(u16x8*)(dlo + 8) = lo1;
}

__global__ __launch_bounds__(256) void prep_kernel(
    const float* __restrict__ Q, const float* __restrict__ K, const float* __restrict__ V,
    unsigned short* __restrict__ Qhi, unsigned short* __restrict__ Qlo,
    unsigned short* __restrict__ Khi, unsigned short* __restrict__ Klo,
    unsigned short* __restrict__ Vthi, unsigned short* __restrict__ Vtlo) {
    __shared__ __align__(16) float vt[64][68];
    const int t  = threadIdx.x;
    const int b  = blockIdx.x >> 6;
    const int l0 = (blockIdx.x & 63) << 6;
    const int r  = t >> 2;
    const int d0 = (t & 3) << 4;

    const size_t src = (size_t)(l0 + r) * (B_ * D_) + (size_t)b * D_ + d0;
    const size_t dst = ((size_t)b * L_ + l0 + r) * D_ + d0;
    convert16(Q + src, 0.125f, Qhi + dst, Qlo + dst);
    convert16(K + src, 1.0f,   Khi + dst, Klo + dst);

    const float* vsrc = V + src;
#pragma unroll
    for (int m = 0; m < 16; m += 4)
        *(f32x4*)&vt[r][d0 + m] = *(const f32x4*)&vsrc[m];
    __syncthreads();

    const int d  = t >> 2;
    const int lp = (t & 3) << 4;
    u16x8 h0, h1, lo0, lo1;
#pragma unroll
    for (int m = 0; m < 16; ++m) {
        float x = vt[lp + m][d];
        unsigned short h = f2bf(x);
        unsigned short l = f2bf(x - bf2f(h));
        if (m < 8) { h0[m] = (short)h; lo0[m] = (short)l; }
        else       { h1[m - 8] = (short)h; lo1[m - 8] = (short)l; }
    }
    unsigned short* oh = Vthi + ((size_t)b * D_ + d) * L_ + l0 + lp;
    unsigned short* ol = Vtlo + ((size_t)b * D_ + d) * L_ + l0 + lp;
    *(u16x8*)(oh) = h0;  *(u16x8*)(oh + 8) = h1;
    *(u16x8*)(ol) = lo0; *(u16x8*)(ol + 8) = lo1;
}

// ---------------------------------------------------------------------------
// stats: row sums l = sum_j exp(s).  Compute-only (no attn write, no PV).
// Swapped MFMA; 128 rows x 512-col chunk per block; K double-buffered.
// Grid: B * 32 * JS = 1024 blocks of 256 threads.
// ---------------------------------------------------------------------------
__global__ __launch_bounds__(256) void stats_kernel(
    const unsigned short* __restrict__ Qhi, const unsigned short* __restrict__ Qlo,
    const unsigned short* __restrict__ Khi, const unsigned short* __restrict__ Klo,
    const int* __restrict__ mask, float* __restrict__ lpart)
{
    __shared__ __align__(16) unsigned short kh[2][64 * 64];   // 16 KB
    __shared__ __align__(16) unsigned short kl[2][64 * 64];   // 16 KB

    const int tid = threadIdx.x;
    const int w = tid >> 6, lane = tid & 63;
    const int lr = lane & 15, lg = lane >> 4;
    const int b  = blockIdx.x >> 8;
    const int it = (blockIdx.x >> 3) & 31;
    const int jc = blockIdx.x & 7;
    const int irow = it * 128 + w * 32;
    const int j0c  = jc * (L_ / JS);

    bf16x8 qh0[2], qh1[2], ql0[2], ql1[2];
#pragma unroll
    for (int rs = 0; rs < 2; ++rs) {
        const size_t qoff = ((size_t)b * L_ + irow + rs * 16 + lr) * D_ + lg * 8;
        qh0[rs] = *(const bf16x8*)(Qhi + qoff);
        qh1[rs] = *(const bf16x8*)(Qhi + qoff + 32);
        ql0[rs] = *(const bf16x8*)(Qlo + qoff);
        ql1[rs] = *(const bf16x8*)(Qlo + qoff + 32);
    }

    float lsum[2] = {0.f, 0.f};
    int buf = 0;
    stage64(Khi + ((size_t)b * L_ + j0c) * D_, kh[0], tid);
    stage64(Klo + ((size_t)b * L_ + j0c) * D_, kl[0], tid);
    __syncthreads();

    for (int st = 0; st < NS; ++st) {
        const int j0 = j0c + st * 64;
        if (st < NS - 1) {      // prefetch next tile into the other buffer
            stage64(Khi + ((size_t)b * L_ + j0 + 64) * D_, kh[buf ^ 1], tid);
            stage64(Klo + ((size_t)b * L_ + j0 + 64) * D_, kl[buf ^ 1], tid);
        }
#pragma unroll
        for (int jj = 0; jj < 4; ++jj) {
            const bf16x8 a_h0 = rdfrag(kh[buf], jj * 16 + lr, lg * 8);
            const bf16x8 a_h1 = rdfrag(kh[buf], jj * 16 + lr, lg * 8 + 32);
            const bf16x8 a_l0 = rdfrag(kl[buf], jj * 16 + lr, lg * 8);
            const bf16x8 a_l1 = rdfrag(kl[buf], jj * 16 + lr, lg * 8 + 32);
            const i32x4 mv = *(const i32x4*)&mask[(size_t)b * L_ + j0 + jj * 16 + lg * 4];
#pragma unroll
            for (int rs = 0; rs < 2; ++rs) {
                f32x4 acc = {0.f, 0.f, 0.f, 0.f};
                acc = MFMA16(a_h0, qh0[rs], acc);
                acc = MFMA16(a_h1, qh1[rs], acc);
                acc = MFMA16(a_h0, ql0[rs], acc);
                acc = MFMA16(a_h1, ql1[rs], acc);
                acc = MFMA16(a_l0, qh0[rs], acc);
                acc = MFMA16(a_l1, qh1[rs], acc);
#pragma unroll
                for (int r = 0; r < 4; ++r)
                    lsum[rs] += __expf(mv[r] ? -1.0e9f : acc[r]);
            }
        }
        __syncthreads();        // next buffer staged; this buffer free
        buf ^= 1;
    }

#pragma unroll
    for (int rs = 0; rs < 2; ++rs) {
        float v = lsum[rs];
        v += __shfl_xor(v, 16, 64);
        v += __shfl_xor(v, 32, 64);
        if (lg == 0)
            lpart[((size_t)b * L_ + irow + rs * 16 + lr) * JS + jc] = v;
    }
}

// ---------------------------------------------------------------------------
// pv: recompute S, p = exp(s) * invl (final value), write attn ONCE,
// PV via MFMA -> atomicAdd normalized partials into zeroed out.
// V fragments prefetched to registers at the top of each step so their
// latency hides under the QK^T + exp phase.
// ---------------------------------------------------------------------------
__global__ __launch_bounds__(256) void pv_kernel(
    const unsigned short* __restrict__ Qhi, const unsigned short* __restrict__ Qlo,
    const unsigned short* __restrict__ Khi, const unsigned short* __restrict__ Klo,
    const unsigned short* __restrict__ Vthi, const unsigned short* __restrict__ Vtlo,
    const int* __restrict__ mask, const float* __restrict__ lpart,
    float* __restrict__ attn, float* __restrict__ out)
{
    __shared__ __align__(16) unsigned short kh[64 * 64];     // 8 KB
    __shared__ __align__(16) unsigned short kl[64 * 64];     // 8 KB
    __shared__ __align__(16) unsigned short phs[4][16][72];  // 9 KB
    __shared__ __align__(16) unsigned short pls[4][16][72];  // 9 KB

    const int tid = threadIdx.x;
    const int w = tid >> 6, lane = tid & 63;
    const int lr = lane & 15, lg = lane >> 4;
    const int b  = blockIdx.x >> 8;
    const int it = (blockIdx.x >> 3) & 31;
    const int jc = blockIdx.x & 7;
    const int irow = it * 128 + w * 32;
    const int j0c  = jc * (L_ / JS);
    const size_t ab = (size_t)b * L_ * L_;

    bf16x8 qh0[2], qh1[2], ql0[2], ql1[2];
    float invl[2];
#pragma unroll
    for (int rs = 0; rs < 2; ++rs) {
        const size_t row = (size_t)b * L_ + irow + rs * 16 + lr;
        const size_t qoff = row * D_ + lg * 8;
        qh0[rs] = *(const bf16x8*)(Qhi + qoff);
        qh1[rs] = *(const bf16x8*)(Qhi + qoff + 32);
        ql0[rs] = *(const bf16x8*)(Qlo + qoff);
        ql1[rs] = *(const bf16x8*)(Qlo + qoff + 32);
        const float* lp = lpart + row * JS;
        f32x4 s0 = *(const f32x4*)lp;
        f32x4 s1 = *(const f32x4*)(lp + 4);
        invl[rs] = 1.0f / (s0[0] + s0[1] + s0[2] + s0[3] + s1[0] + s1[1] + s1[2] + s1[3]);
    }

    f32x4 oacc[2][4];
#pragma unroll
    for (int rs = 0; rs < 2; ++rs)
#pragma unroll
        for (int dv = 0; dv < 4; ++dv) oacc[rs][dv] = (f32x4){0.f, 0.f, 0.f, 0.f};

    for (int st = 0; st < NS; ++st) {
        const int j0 = j0c + st * 64;
        __syncthreads();                              // K buf free
        stage64(Khi + ((size_t)b * L_ + j0) * D_, kh, tid);
        stage64(Klo + ((size_t)b * L_ + j0) * D_, kl, tid);
        __syncthreads();                              // staged data visible

        // prefetch V (kk=0 half) -- latency hides under QK^T below
        bf16x8 v0h[4], v0l[4];
#pragma unroll
        for (int dv = 0; dv < 4; ++dv) {
            const size_t voff = ((size_t)b * D_ + dv * 16 + lr) * L_ + j0 + lg * 8;
            v0h[dv] = *(const bf16x8*)(Vthi + voff);
            v0l[dv] = *(const bf16x8*)(Vtlo + voff);
        }

        i32x4 mv[4];
#pragma unroll
        for (int jj = 0; jj < 4; ++jj)
            mv[jj] = *(const i32x4*)&mask[(size_t)b * L_ + j0 + jj * 16 + lg * 4];

        bf16x8 P[2][4];                               // [rs][kk*2 + {hi,lo}]
#pragma unroll
        for (int rs = 0; rs < 2; ++rs) {
#pragma unroll
            for (int jj = 0; jj < 4; ++jj) {
                const bf16x8 a_h0 = rdfrag(kh, jj * 16 + lr, lg * 8);
                const bf16x8 a_h1 = rdfrag(kh, jj * 16 + lr, lg * 8 + 32);
                const bf16x8 a_l0 = rdfrag(kl, jj * 16 + lr, lg * 8);
                const bf16x8 a_l1 = rdfrag(kl, jj * 16 + lr, lg * 8 + 32);
                f32x4 acc = {0.f, 0.f, 0.f, 0.f};
                acc = MFMA16(a_h0, qh0[rs], acc);
                acc = MFMA16(a_h1, qh1[rs], acc);
                acc = MFMA16(a_h0, ql0[rs], acc);
                acc = MFMA16(a_h1, ql1[rs], acc);
                acc = MFMA16(a_l0, qh0[rs], acc);
                acc = MFMA16(a_l1, qh1[rs], acc);
                f32x4 p4;
                u16x4 hv, lv;
#pragma unroll
                for (int r = 0; r < 4; ++r) {
                    const float e = __expf(mv[jj][r] ? -1.0e9f : acc[r]);
                    const float p = e * invl[rs];     // final normalized value
                    p4[r] = p;
                    const unsigned short h = f2bf(p);
                    hv[r] = h;
                    lv[r] = f2bf(p - bf2f(h));
                }
                *(f32x4*)&attn[ab + (size_t)(irow + rs * 16 + lr) * L_ + j0 + jj * 16 + lg * 4] = p4;
                *(u16x4*)&phs[w][lr][jj * 16 + lg * 4] = hv;
                *(u16x4*)&pls[w][lr][jj * 16 + lg * 4] = lv;
            }
            P[rs][0] = *(const bf16x8*)&phs[w][lr][lg * 8];
            P[rs][1] = *(const bf16x8*)&pls[w][lr][lg * 8];
            P[rs][2] = *(const bf16x8*)&phs[w][lr][32 + lg * 8];
            P[rs][3] = *(const bf16x8*)&pls[w][lr][32 + lg * 8];
        }

        // prefetch V (kk=1 half) -- hides under PV kk=0 MFMAs
        bf16x8 v1h[4], v1l[4];
#pragma unroll
        for (int dv = 0; dv < 4; ++dv) {
            const size_t voff = ((size_t)b * D_ + dv * 16 + lr) * L_ + j0 + 32 + lg * 8;
            v1h[dv] = *(const bf16x8*)(Vthi + voff);
            v1l[dv] = *(const bf16x8*)(Vtlo + voff);
        }

#pragma unroll
        for (int dv = 0; dv < 4; ++dv)
#pragma unroll
            for (int rs = 0; rs < 2; ++rs) {
                oacc[rs][dv] = MFMA16(v0h[dv], P[rs][0], oacc[rs][dv]);
                oacc[rs][dv] = MFMA16(v0h[dv], P[rs][1], oacc[rs][dv]);
                oacc[rs][dv] = MFMA16(v0l[dv], P[rs][0], oacc[rs][dv]);
            }
#pragma unroll
        for (int dv = 0; dv < 4; ++dv)
#pragma unroll
            for (int rs = 0; rs < 2; ++rs) {
                oacc[rs][dv] = MFMA16(v1h[dv], P[rs][2], oacc[rs][dv]);
                oacc[rs][dv] = MFMA16(v1h[dv], P[rs][3], oacc[rs][dv]);
                oacc[rs][dv] = MFMA16(v1l[dv], P[rs][2], oacc[rs][dv]);
            }
    }

#pragma unroll
    for (int rs = 0; rs < 2; ++rs)
#pragma unroll
        for (int dv = 0; dv < 4; ++dv) {
            const size_t obase = (size_t)(irow + rs * 16 + lr) * (B_ * D_) + b * D_ + dv * 16 + lg * 4;
#pragma unroll
            for (int r = 0; r < 4; ++r)
                atomicAdd(&out[obase + r], oacc[rs][dv][r]);
        }
}

// ---------------------------------------------------------------------------
extern "C" void kernel_launch(void* const* d_in, const int* in_sizes, int n_in,
                              void* d_out, int out_size, void* d_ws, size_t ws_size,
                              hipStream_t stream) {
    const float* Q   = (const float*)d_in[0];
    const float* K   = (const float*)d_in[1];
    const float* V   = (const float*)d_in[2];
    const int*  mask = (const int*)d_in[3];     // jnp.bool_ -> int32 (validated R1)

    float* out  = (float*)d_out;                             // [L, B, D]
    float* attn = (float*)d_out + (size_t)L_ * B_ * D_;      // [B, L, L]

    const size_t NE = (size_t)B_ * L_ * D_;
    unsigned short* Qhi  = (unsigned short*)d_ws;
    unsigned short* Qlo  = Qhi + NE;
    unsigned short* Khi  = Qhi + 2 * NE;
    unsigned short* Klo  = Qhi + 3 * NE;
    unsigned short* Vthi = Qhi + 4 * NE;
    unsigned short* Vtlo = Qhi + 5 * NE;
    float* lpart = (float*)((char*)d_ws + 6 * NE * sizeof(unsigned short)); // [B*L][JS]

    hipLaunchKernelGGL(zero_out_kernel, dim3((L_ * B_ * D_) / (256 * 4)), dim3(256), 0, stream, out);
    hipLaunchKernelGGL(prep_kernel, dim3(B_ * (L_ / 64)), dim3(256), 0, stream,
                       Q, K, V, Qhi, Qlo, Khi, Klo, Vthi, Vtlo);
    hipLaunchKernelGGL(stats_kernel, dim3(B_ * (L_ / 128) * JS), dim3(256), 0, stream,
                       Qhi, Qlo, Khi, Klo, mask, lpart);
    hipLaunchKernelGGL(pv_kernel, dim3(B_ * (L_ / 128) * JS), dim3(256), 0, stream,
                       Qhi, Qlo, Khi, Klo, Vthi, Vtlo, mask, lpart, attn, out);
}